// Round 1
// baseline (113.791 us; speedup 1.0000x reference)
//
#include <hip/hip_runtime.h>

#define GROUPS 64
#define DIMS 8
#define ACCW 10            // gacc words per (img,group): 8 dims + ssq + count
#define COPIES 16          // LDS accumulator copies (one per 4-lane cluster)
#define GSTRIDE 5          // u64 words per group in LDS: 4 dim-pairs + (ssq|count)
#define BPI 128            // blocks per image
#define BLK 256
#define NIMG 8
#define SCALE 262144.0f            // 2^18
#define INV_SCALE (1.0f / 262144.0f)
#define MAGICF 12582912.0f         // 2^23 + 2^22: RNE-to-int + bias in one fma

// field = rne(x * 2^18) + 2^22, exact, 2 VALU ops (fma + and)
__device__ __forceinline__ unsigned int fieldOf(float x) {
    return __float_as_uint(fmaf(x, SCALE, MAGICF)) & 0x007FFFFFu;
}

__global__ __launch_bounds__(BLK) void k_accum(const float* __restrict__ pred,
                                               const int* __restrict__ gt,
                                               unsigned long long* __restrict__ gacc,
                                               unsigned long long* __restrict__ ticket,
                                               float* __restrict__ out,
                                               int N) {
    __shared__ unsigned long long accw[COPIES][GROUPS * GSTRIDE];  // 40960 B
    __shared__ int isLast;
    const int tid = threadIdx.x;
    const int b = blockIdx.y;

    for (int i = tid; i < COPIES * GROUPS * GSTRIDE; i += BLK)
        ((unsigned long long*)accw)[i] = 0ull;
    __syncthreads();

    const float4* pb = (const float4*)(pred + (size_t)b * N * DIMS);
    const int* gb = gt + (size_t)b * N;
    unsigned long long* myacc = &accw[(tid >> 2) & (COPIES - 1)][0];

    for (int idx = blockIdx.x * BLK + tid; idx < N; idx += BPI * BLK) {
        int g = gb[idx];
        float4 p0 = pb[2 * idx];
        float4 p1 = pb[2 * idx + 1];
        unsigned long long* a = myacc + g * GSTRIDE;
        atomicAdd(a + 0, (unsigned long long)fieldOf(p0.x) | ((unsigned long long)fieldOf(p0.y) << 32));
        atomicAdd(a + 1, (unsigned long long)fieldOf(p0.z) | ((unsigned long long)fieldOf(p0.w) << 32));
        atomicAdd(a + 2, (unsigned long long)fieldOf(p1.x) | ((unsigned long long)fieldOf(p1.y) << 32));
        atomicAdd(a + 3, (unsigned long long)fieldOf(p1.z) | ((unsigned long long)fieldOf(p1.w) << 32));
        float ssq = p0.x*p0.x + p0.y*p0.y + p0.z*p0.z + p0.w*p0.w
                  + p1.x*p1.x + p1.y*p1.y + p1.z*p1.z + p1.w*p1.w;
        unsigned int si = (unsigned int)__float2int_rn(ssq * SCALE);
        atomicAdd(a + 4, (unsigned long long)si | (1ull << 32));   // lo=ssq, hi=count+1
    }
    __syncthreads();

    // block-level reduce over copies (unbias dims with packed count) -> global atomics
    for (int i = tid; i < GROUPS * ACCW; i += BLK) {
        int g = i / ACCW, k = i % ACCW;
        long long v = 0;
        if (k < 8) {
            int w = k >> 1, hi = k & 1;
            for (int c = 0; c < COPIES; ++c) {
                unsigned long long pw = accw[c][g * GSTRIDE + w];
                unsigned long long cw = accw[c][g * GSTRIDE + 4];
                unsigned int f = hi ? (unsigned int)(pw >> 32) : (unsigned int)pw;
                v += (long long)f - (long long)((cw >> 32) << 22);
            }
        } else if (k == 8) {
            for (int c = 0; c < COPIES; ++c)
                v += (long long)(unsigned int)accw[c][g * GSTRIDE + 4];
        } else {
            for (int c = 0; c < COPIES; ++c)
                v += (long long)(accw[c][g * GSTRIDE + 4] >> 32);
        }
        atomicAdd(&gacc[(b * GROUPS + g) * ACCW + k], (unsigned long long)v);
    }

    // last-block-done ticket: fuse the finalize, saving a kernel launch
    __threadfence();
    __syncthreads();
    if (tid == 0) {
        unsigned long long t = atomicAdd(ticket, 1ull);
        isLast = (t == (unsigned long long)(gridDim.x * gridDim.y) - 1ull) ? 1 : 0;
    }
    __syncthreads();
    if (!isLast) return;
    __threadfence();

    // ---------- finisher (runs once, in the last block) ----------
    float* smf = (float*)&accw[0][0];                 // reuse LDS: [NIMG][GROUPS][DIMS+1]
    float* lossF = smf + NIMG * GROUPS * (DIMS + 1);  // 8 floats, still inside 40 KB
    const int wv = tid >> 6;
    const int g = tid & 63;
    for (int ib = wv; ib < NIMG; ib += 4) {           // each wave handles 2 images
        unsigned long long ga[ACCW];
        const unsigned long long* gp = gacc + (ib * GROUPS + g) * ACCW;
        for (int k = 0; k < ACCW; ++k)
            ga[k] = __hip_atomic_load(gp + k, __ATOMIC_RELAXED, __HIP_MEMORY_SCOPE_AGENT);
        float c = (float)(long long)ga[9];
        float ssq = (float)(long long)ga[8] * INV_SCALE;
        float safe = fmaxf(c, 1.f);
        float m[DIMS];
        float msq = 0.f;
        float* row = smf + (ib * GROUPS + g) * (DIMS + 1);
        for (int d = 0; d < DIMS; ++d) {
            m[d] = ((float)(long long)ga[d] * INV_SCALE) / safe;
            row[d] = m[d];
            msq += m[d] * m[d];
        }
        bool present = c > 0.f;
        row[DIMS] = present ? 1.f : 0.f;

        float sumsq = ssq - c * msq;
        float pull_g = present ? sumsq / (safe * (float)DIMS) : 0.f;

        unsigned long long mask = __ballot(present);
        float num = (float)__popcll(mask);

        float pull = pull_g;
        for (int off = 32; off; off >>= 1) pull += __shfl_xor(pull, off);

        float pg = 0.f;
        if (present) {
            for (int j = 0; j < GROUPS; ++j) {
                const float* rj = smf + (ib * GROUPS + j) * (DIMS + 1);
                float pm = rj[DIMS];
                float d2 = 0.f;
                for (int d = 0; d < DIMS; ++d) {
                    float t2 = m[d] - rj[d];
                    d2 += t2 * t2;
                }
                pg += pm * expf(-d2);
            }
        }
        for (int off = 32; off; off >>= 1) pg += __shfl_xor(pg, off);

        if (g == 0) {
            float push = (pg - num) / ((num - 1.f) * num + 1e-6f) * 0.5f;
            lossF[ib] = push + pull / (num + 1e-6f);
        }
    }
    __syncthreads();
    if (tid == 0) {
        float s = 0.f;
        for (int i = 0; i < NIMG; ++i) s += lossF[i];
        out[0] = s * (1.f / (float)NIMG);
    }
}

extern "C" void kernel_launch(void* const* d_in, const int* in_sizes, int n_in,
                              void* d_out, int out_size, void* d_ws, size_t ws_size,
                              hipStream_t stream) {
    const float* pred = (const float*)d_in[0];
    const int* gt = (const int*)d_in[1];
    const int N = in_sizes[1] / NIMG;   // 500000

    unsigned long long* gacc = (unsigned long long*)d_ws;      // [NIMG][GROUPS][ACCW]
    unsigned long long* ticket = gacc + NIMG * GROUPS * ACCW;  // 1 word after

    hipMemsetAsync(d_ws, 0, (NIMG * GROUPS * ACCW + 1) * sizeof(unsigned long long), stream);

    dim3 grid(BPI, NIMG);
    k_accum<<<grid, BLK, 0, stream>>>(pred, gt, gacc, ticket, (float*)d_out, N);
}

// Round 2
// 73.779 us; speedup vs baseline: 1.5423x; 1.5423x over previous
//
#include <hip/hip_runtime.h>

#define GROUPS 64
#define DIMS 8
#define ACCW 10      // 8 sums + ssq + count
#define LSTRIDE 11   // LDS int stride (break pow2 bank pattern)
#define BPI 128      // blocks per image
#define BLK 256
#define NIMG 8
#define SCALE 262144.0f          // 2^18
#define INV_SCALE (1.0f / 262144.0f)

__global__ __launch_bounds__(BLK) void k_accum(const float* __restrict__ pred,
                                               const int* __restrict__ gt,
                                               unsigned long long* __restrict__ gacc,
                                               unsigned long long* __restrict__ ticket,
                                               float* __restrict__ out,
                                               int N) {
    __shared__ int acc[4][GROUPS * LSTRIDE];           // 11264 B (proven round-0 layout)
    __shared__ float smf[NIMG][GROUPS][DIMS + 1];      // 18432 B (finisher means table)
    __shared__ float lossArr[NIMG];
    __shared__ int isLast;

    const int tid = threadIdx.x;
    const int wave = tid >> 6;
    const int b = blockIdx.y;
    for (int i = tid; i < 4 * GROUPS * LSTRIDE; i += BLK) ((int*)acc)[i] = 0;
    __syncthreads();

    const float4* pb = (const float4*)(pred + (size_t)b * N * DIMS);
    const int* gb = gt + (size_t)b * N;
    for (int idx = blockIdx.x * BLK + tid; idx < N; idx += BPI * BLK) {
        int g = gb[idx];
        float4 p0 = pb[2 * idx];
        float4 p1 = pb[2 * idx + 1];
        int* a = &acc[wave][g * LSTRIDE];
        atomicAdd(a + 0, __float2int_rn(p0.x * SCALE));
        atomicAdd(a + 1, __float2int_rn(p0.y * SCALE));
        atomicAdd(a + 2, __float2int_rn(p0.z * SCALE));
        atomicAdd(a + 3, __float2int_rn(p0.w * SCALE));
        atomicAdd(a + 4, __float2int_rn(p1.x * SCALE));
        atomicAdd(a + 5, __float2int_rn(p1.y * SCALE));
        atomicAdd(a + 6, __float2int_rn(p1.z * SCALE));
        atomicAdd(a + 7, __float2int_rn(p1.w * SCALE));
        float ssq = p0.x*p0.x + p0.y*p0.y + p0.z*p0.z + p0.w*p0.w
                  + p1.x*p1.x + p1.y*p1.y + p1.z*p1.z + p1.w*p1.w;
        atomicAdd(a + 8, __float2int_rn(ssq * SCALE));
        atomicAdd(a + 9, 1);
    }
    __syncthreads();

    for (int i = tid; i < GROUPS * ACCW; i += BLK) {
        int g = i / ACCW, k = i % ACCW;
        long long v = (long long)acc[0][g * LSTRIDE + k]
                    + (long long)acc[1][g * LSTRIDE + k]
                    + (long long)acc[2][g * LSTRIDE + k]
                    + (long long)acc[3][g * LSTRIDE + k];
        atomicAdd(&gacc[(b * GROUPS + g) * ACCW + k], (unsigned long long)v);
    }

    // __syncthreads drains vmcnt(0) for every wave before the barrier, so all of this
    // block's gacc atomics are complete before tid 0 bumps the ticket (acq_rel).
    __syncthreads();
    if (tid == 0) {
        unsigned long long t = __hip_atomic_fetch_add(ticket, 1ull, __ATOMIC_ACQ_REL,
                                                      __HIP_MEMORY_SCOPE_AGENT);
        isLast = (t == (unsigned long long)(BPI * NIMG) - 1ull) ? 1 : 0;
    }
    __syncthreads();
    if (!isLast) return;

    // ---------- finisher: runs once in the last block (verified numerics, round 1) ----------
    const int wv = tid >> 6;
    const int g = tid & 63;
    for (int ib = wv; ib < NIMG; ib += 4) {            // each wave handles 2 images
        unsigned long long ga[ACCW];
        const unsigned long long* gp = gacc + (ib * GROUPS + g) * ACCW;
        for (int k = 0; k < ACCW; ++k)
            ga[k] = __hip_atomic_load(gp + k, __ATOMIC_RELAXED, __HIP_MEMORY_SCOPE_AGENT);
        float c = (float)(long long)ga[9];
        float ssq = (float)(long long)ga[8] * INV_SCALE;
        float safe = fmaxf(c, 1.f);
        float m[DIMS];
        float msq = 0.f;
        for (int d = 0; d < DIMS; ++d) {
            m[d] = ((float)(long long)ga[d] * INV_SCALE) / safe;
            smf[ib][g][d] = m[d];
            msq += m[d] * m[d];
        }
        bool present = c > 0.f;
        smf[ib][g][DIMS] = present ? 1.f : 0.f;

        float sumsq = ssq - c * msq;
        float pull_g = present ? sumsq / (safe * (float)DIMS) : 0.f;

        unsigned long long mask = __ballot(present);
        float num = (float)__popcll(mask);

        float pull = pull_g;
        for (int off = 32; off; off >>= 1) pull += __shfl_xor(pull, off);

        float pg = 0.f;
        if (present) {
            for (int j = 0; j < GROUPS; ++j) {
                float pm = smf[ib][j][DIMS];
                float d2 = 0.f;
                for (int d = 0; d < DIMS; ++d) {
                    float t2 = m[d] - smf[ib][j][d];
                    d2 += t2 * t2;
                }
                pg += pm * expf(-d2);
            }
        }
        for (int off = 32; off; off >>= 1) pg += __shfl_xor(pg, off);

        if (g == 0) {
            float push = (pg - num) / ((num - 1.f) * num + 1e-6f) * 0.5f;
            lossArr[ib] = push + pull / (num + 1e-6f);
        }
    }
    __syncthreads();
    if (tid == 0) {
        float s = 0.f;
        for (int i = 0; i < NIMG; ++i) s += lossArr[i];
        out[0] = s * (1.f / (float)NIMG);
    }
}

extern "C" void kernel_launch(void* const* d_in, const int* in_sizes, int n_in,
                              void* d_out, int out_size, void* d_ws, size_t ws_size,
                              hipStream_t stream) {
    const float* pred = (const float*)d_in[0];
    const int* gt = (const int*)d_in[1];
    const int N = in_sizes[1] / NIMG;   // 500000

    unsigned long long* gacc = (unsigned long long*)d_ws;      // [NIMG][GROUPS][ACCW]
    unsigned long long* ticket = gacc + NIMG * GROUPS * ACCW;  // 1 word after

    hipMemsetAsync(d_ws, 0, (NIMG * GROUPS * ACCW + 1) * sizeof(unsigned long long), stream);

    dim3 grid(BPI, NIMG);
    k_accum<<<grid, BLK, 0, stream>>>(pred, gt, gacc, ticket, (float*)d_out, N);
}

// Round 3
// 52.162 us; speedup vs baseline: 2.1815x; 1.4144x over previous
//
#include <hip/hip_runtime.h>

#define GROUPS 64
#define DIMS 8
#define ACCW 10      // 8 sums + ssq + count
#define LSTRIDE 11   // LDS int stride (break pow2 bank pattern)
#define BPI 128      // blocks per image
#define BLK 512      // 8 waves/block -> 32 waves/CU at 4 blocks/CU (grid = 1024)
#define WAVES 8
#define NIMG 8
#define SCALE 262144.0f          // 2^18
#define INV_SCALE (1.0f / 262144.0f)

__global__ __launch_bounds__(BLK, 8) void k_accum(const float* __restrict__ pred,
                                                  const int* __restrict__ gt,
                                                  unsigned long long* __restrict__ gacc,
                                                  unsigned long long* __restrict__ ticket,
                                                  float* __restrict__ out,
                                                  int N) {
    __shared__ int acc[WAVES][GROUPS * LSTRIDE];   // 22528 B; finisher reuses as smf
    __shared__ float lossArr[NIMG];
    __shared__ int isLast;

    const int tid = threadIdx.x;
    const int wave = tid >> 6;
    const int b = blockIdx.y;
    for (int i = tid; i < WAVES * GROUPS * LSTRIDE; i += BLK) ((int*)acc)[i] = 0;
    __syncthreads();

    const float4* pb = (const float4*)(pred + (size_t)b * N * DIMS);
    const int* gb = gt + (size_t)b * N;
    for (int idx = blockIdx.x * BLK + tid; idx < N; idx += BPI * BLK) {
        int g = gb[idx];
        float4 p0 = pb[2 * idx];
        float4 p1 = pb[2 * idx + 1];
        int* a = &acc[wave][g * LSTRIDE];
        atomicAdd(a + 0, __float2int_rn(p0.x * SCALE));
        atomicAdd(a + 1, __float2int_rn(p0.y * SCALE));
        atomicAdd(a + 2, __float2int_rn(p0.z * SCALE));
        atomicAdd(a + 3, __float2int_rn(p0.w * SCALE));
        atomicAdd(a + 4, __float2int_rn(p1.x * SCALE));
        atomicAdd(a + 5, __float2int_rn(p1.y * SCALE));
        atomicAdd(a + 6, __float2int_rn(p1.z * SCALE));
        atomicAdd(a + 7, __float2int_rn(p1.w * SCALE));
        float ssq = p0.x*p0.x + p0.y*p0.y + p0.z*p0.z + p0.w*p0.w
                  + p1.x*p1.x + p1.y*p1.y + p1.z*p1.z + p1.w*p1.w;
        atomicAdd(a + 8, __float2int_rn(ssq * SCALE));
        atomicAdd(a + 9, 1);
    }
    __syncthreads();

    for (int i = tid; i < GROUPS * ACCW; i += BLK) {
        int g = i / ACCW, k = i % ACCW;
        long long v = 0;
        for (int c = 0; c < WAVES; ++c) v += (long long)acc[c][g * LSTRIDE + k];
        atomicAdd(&gacc[(b * GROUPS + g) * ACCW + k], (unsigned long long)v);
    }

    // __syncthreads drains vmcnt(0) per wave, so this block's device-scope gacc
    // atomics are complete at the coherent point before the ticket RMW below.
    // RELAXED (not acq_rel): an agent-scope release/acquire would emit an L2
    // writeback+invalidate per block on gfx950 (non-coherent per-XCD L2) --
    // that flush storm was the round-1/2 regression.
    __syncthreads();
    if (tid == 0) {
        unsigned long long t = __hip_atomic_fetch_add(ticket, 1ull, __ATOMIC_RELAXED,
                                                      __HIP_MEMORY_SCOPE_AGENT);
        isLast = (t == (unsigned long long)(BPI * NIMG) - 1ull) ? 1 : 0;
    }
    __syncthreads();
    if (!isLast) return;

    // ---------- finisher: runs once in the last block ----------
    float (*smf)[DIMS + 1] = (float (*)[DIMS + 1])(&acc[0][0]);  // [NIMG*GROUPS][9], 18432 B <= 22528 B
    const int ib = tid >> 6;    // one wave per image (8 waves, 8 images)
    const int g = tid & 63;

    unsigned long long ga[ACCW];
    const unsigned long long* gp = gacc + (ib * GROUPS + g) * ACCW;
    for (int k = 0; k < ACCW; ++k)
        ga[k] = __hip_atomic_load(gp + k, __ATOMIC_RELAXED, __HIP_MEMORY_SCOPE_AGENT);
    float c = (float)(long long)ga[9];
    float ssq = (float)(long long)ga[8] * INV_SCALE;
    float safe = fmaxf(c, 1.f);
    float m[DIMS];
    float msq = 0.f;
    for (int d = 0; d < DIMS; ++d) {
        m[d] = ((float)(long long)ga[d] * INV_SCALE) / safe;
        smf[ib * GROUPS + g][d] = m[d];
        msq += m[d] * m[d];
    }
    bool present = c > 0.f;
    smf[ib * GROUPS + g][DIMS] = present ? 1.f : 0.f;

    float sumsq = ssq - c * msq;
    float pull_g = present ? sumsq / (safe * (float)DIMS) : 0.f;

    unsigned long long mask = __ballot(present);
    float num = (float)__popcll(mask);

    float pull = pull_g;
    for (int off = 32; off; off >>= 1) pull += __shfl_xor(pull, off);

    __syncthreads();   // means table complete for all 8 images

    float pg = 0.f;
    if (present) {
        for (int j = 0; j < GROUPS; ++j) {
            const float* rj = smf[ib * GROUPS + j];
            float pm = rj[DIMS];
            float d2 = 0.f;
            for (int d = 0; d < DIMS; ++d) {
                float t2 = m[d] - rj[d];
                d2 += t2 * t2;
            }
            pg += pm * expf(-d2);
        }
    }
    for (int off = 32; off; off >>= 1) pg += __shfl_xor(pg, off);

    if (g == 0) {
        float push = (pg - num) / ((num - 1.f) * num + 1e-6f) * 0.5f;
        lossArr[ib] = push + pull / (num + 1e-6f);
    }
    __syncthreads();
    if (tid == 0) {
        float s = 0.f;
        for (int i = 0; i < NIMG; ++i) s += lossArr[i];
        out[0] = s * (1.f / (float)NIMG);
    }
}

extern "C" void kernel_launch(void* const* d_in, const int* in_sizes, int n_in,
                              void* d_out, int out_size, void* d_ws, size_t ws_size,
                              hipStream_t stream) {
    const float* pred = (const float*)d_in[0];
    const int* gt = (const int*)d_in[1];
    const int N = in_sizes[1] / NIMG;   // 500000

    unsigned long long* gacc = (unsigned long long*)d_ws;      // [NIMG][GROUPS][ACCW]
    unsigned long long* ticket = gacc + NIMG * GROUPS * ACCW;  // 1 word after

    hipMemsetAsync(d_ws, 0, (NIMG * GROUPS * ACCW + 1) * sizeof(unsigned long long), stream);

    dim3 grid(BPI, NIMG);
    k_accum<<<grid, BLK, 0, stream>>>(pred, gt, gacc, ticket, (float*)d_out, N);
}